// Round 1
// baseline (316.482 us; speedup 1.0000x reference)
//
#include <hip/hip_runtime.h>
#include <math.h>

// Problem constants (from reference)
#define TRAJ_NUM 25
#define T_SAMPLES 10     // int(30*0.66) - int(30*0.33)
#define LOS 10
#define G 200            // voxels per axis
#define VFOV_C 0.17453292519943295f   // deg2rad(20)/... actually rad(20deg) -- set below properly

// VFOV = deg2rad(20.0) = 0.3490658503988659
#define VFOV_RAD 0.3490658503988659f

__global__ __launch_bounds__(128) void trackloss_kernel(
    const float* __restrict__ Df,      // [B,3,3]
    const float* __restrict__ Dp,      // [B,3,3]
    const float* __restrict__ goal,    // [B,3]
    const float* __restrict__ L,       // [6,6]
    const float* __restrict__ sdf,     // [M,200,200,200] (z,y,x)
    const float* __restrict__ minb,    // [M,3]
    const int*   __restrict__ map_id,  // [outer]
    float* __restrict__ out)           // [B]
{
    const int b     = blockIdx.x;          // trajectory index, 0..6399
    const int outer = b / TRAJ_NUM;
    const int tid   = threadIdx.x;

    // --- block-uniform scalar loads ---
    const int m = map_id[outer];
    const float gwx = goal[(outer * TRAJ_NUM) * 3 + 0];
    const float gwy = goal[(outer * TRAJ_NUM) * 3 + 1];
    const float gwz = goal[(outer * TRAJ_NUM) * 3 + 2];
    const float mbx = minb[m * 3 + 0];
    const float mby = minb[m * 3 + 1];
    const float mbz = minb[m * 3 + 2];

    // --- quintic coefficients per axis: coe[c][i] = sum_j L[i][j] * d[c][j] ---
    // d[c][j] = Df[b][c][j] (j<3) else Dp[b][c][j-3]
    float coe[3][6];
    #pragma unroll
    for (int c = 0; c < 3; ++c) {
        float d[6];
        #pragma unroll
        for (int j = 0; j < 3; ++j) {
            d[j]     = Df[b * 9 + c * 3 + j];
            d[j + 3] = Dp[b * 9 + c * 3 + j];
        }
        #pragma unroll
        for (int i = 0; i < 6; ++i) {
            float acc = 0.f;
            #pragma unroll
            for (int j = 0; j < 6; ++j)
                acc += L[i * 6 + j] * d[j];
            coe[c][i] = acc;
        }
    }

    float val = 0.f;
    if (tid < T_SAMPLES * LOS) {
        const int t_i = tid / LOS;   // 0..9
        const int s_i = tid % LOS;   // 0..9

        // t = linspace(0.66, 1.32, 10)
        const float t = (float)(0.66 + (double)t_i * (0.66 / 9.0));

        // position via Horner: sum_k t^k coe[k]
        float p[3], v[3];
        #pragma unroll
        for (int c = 0; c < 3; ++c) {
            float pc = coe[c][5];
            pc = pc * t + coe[c][4];
            pc = pc * t + coe[c][3];
            pc = pc * t + coe[c][2];
            pc = pc * t + coe[c][1];
            pc = pc * t + coe[c][0];
            p[c] = pc;
            // velocity: sum_k t^k (k+1) coe[k+1]
            float vc = 5.f * coe[c][5];
            vc = vc * t + 4.f * coe[c][4];
            vc = vc * t + 3.f * coe[c][3];
            vc = vc * t + 2.f * coe[c][2];
            vc = vc * t + 1.f * coe[c][1];
            v[c] = vc;
        }

        // pitch penalty (added once per t, by the s==0 thread)
        const float gdx = gwx - p[0], gdy = gwy - p[1], gdz = gwz - p[2];
        const float pitch_g = atan2f(gdz, sqrtf(gdx * gdx + gdy * gdy + 1e-6f));
        const float pitch_v = atan2f(v[2], sqrtf(v[0] * v[0] + v[1] * v[1] + 1e-6f));
        const float pen = fmaxf(fabsf(pitch_g - pitch_v) - VFOV_RAD, 0.f);

        // line-of-sight point: p + tt*(goal - p), tt = s/9
        const float tt = (float)s_i * (1.f / 9.f);
        const float px = p[0] + tt * (gwx - p[0]);
        const float py = p[1] + tt * (gwy - p[1]);
        const float pz = p[2] + tt * (gwz - p[2]);

        // voxel-grid coords
        const float gx = (px - mbx) / 0.2f;
        const float gy = (py - mby) / 0.2f;
        const float gz = (pz - mbz) / 0.2f;

        const bool valid = (gx > 0.5f) & (gx < (float)G - 1.5f) &
                           (gy > 0.5f) & (gy < (float)G - 1.5f) &
                           (gz > 0.5f) & (gz < (float)G - 1.5f);

        const float fx0 = floorf(gx), fy0 = floorf(gy), fz0 = floorf(gz);
        const int x0 = (int)fminf(fmaxf(fx0, 0.f), (float)(G - 2));
        const int y0 = (int)fminf(fmaxf(fy0, 0.f), (float)(G - 2));
        const int z0 = (int)fminf(fmaxf(fz0, 0.f), (float)(G - 2));
        const float fx = gx - (float)x0;
        const float fy = gy - (float)y0;
        const float fz = gz - (float)z0;

        const long long base = (((long long)m * G + z0) * G + y0) * G + x0;
        const float c000 = sdf[base];
        const float c001 = sdf[base + 1];
        const float c010 = sdf[base + G];
        const float c011 = sdf[base + G + 1];
        const float c100 = sdf[base + G * G];
        const float c101 = sdf[base + G * G + 1];
        const float c110 = sdf[base + G * G + G];
        const float c111 = sdf[base + G * G + G + 1];

        const float c0 = (c000 * (1.f - fx) + c001 * fx) * (1.f - fy)
                       + (c010 * (1.f - fx) + c011 * fx) * fy;
        const float c1 = (c100 * (1.f - fx) + c101 * fx) * (1.f - fy)
                       + (c110 * (1.f - fx) + c111 * fx) * fy;
        const float dist = c0 * (1.f - fz) + c1 * fz;

        const float cost = valid ? expf((0.6f - dist) * (1.f / 0.3f)) : 0.f;

        // occ contribution: relu(0.2 - cost); final scale 4*5/100 = 0.2
        val = fmaxf(0.2f - cost, 0.f) * 0.2f;
        // pitch contribution: scale 5/10 = 0.5, once per t
        if (s_i == 0) val += pen * 0.5f;
    }

    // --- block reduction (2 waves of 64) ---
    #pragma unroll
    for (int off = 32; off > 0; off >>= 1)
        val += __shfl_down(val, off, 64);

    __shared__ float red[2];
    if ((tid & 63) == 0) red[tid >> 6] = val;
    __syncthreads();
    if (tid == 0) out[b] = red[0] + red[1];
}

extern "C" void kernel_launch(void* const* d_in, const int* in_sizes, int n_in,
                              void* d_out, int out_size, void* d_ws, size_t ws_size,
                              hipStream_t stream) {
    const float* Df     = (const float*)d_in[0];
    const float* Dp     = (const float*)d_in[1];
    const float* goal   = (const float*)d_in[2];
    const float* L      = (const float*)d_in[3];
    const float* sdf    = (const float*)d_in[4];
    const float* minb   = (const float*)d_in[5];
    const int*   map_id = (const int*)d_in[6];
    float* out = (float*)d_out;

    const int B = out_size;  // 6400
    trackloss_kernel<<<B, 128, 0, stream>>>(Df, Dp, goal, L, sdf, minb, map_id, out);
}